// Round 9
// baseline (308.509 us; speedup 1.0000x reference)
//
#include <hip/hip_runtime.h>
#include <hip/hip_cooperative_groups.h>
#include <stdint.h>

namespace cg = cooperative_groups;

#define B_    64
#define N_    512
#define M2    52      // M_PARAM + 2
#define MLPH  128
#define NACT  512
#define FC_IN 2204    // 512 + 512*3 + 52*3
#define KQTR  551     // FC_IN / 4
#define NEG   0.2f
#define NW    16      // mask words per target (512/32)

__device__ __forceinline__ float lrelu(float v){ return v > 0.f ? v : NEG * v; }

// ---- One cooperative kernel: 256 blocks x 1024 threads, block = (b, quarter q) ----
// P1: adj cols -> bits + GAT1 agg + transform2   (q = 128-target j-quarter)
// P2: GAT2 aggregation for the j-quarter
// P3: MLP layer 1, k-range [551q, 551q+551)
// P4: MLP layer 2, output quarter [128q, 128q+128)
__global__ __launch_bounds__(1024) void kmega(
    const float* __restrict__ adj, const float* __restrict__ x,
    const float* __restrict__ idx, const float* __restrict__ y,
    const float* __restrict__ W1,  const float* __restrict__ as1,
    const float* __restrict__ ad1, const float* __restrict__ b1,
    const float* __restrict__ W2,  const float* __restrict__ as2,
    const float* __restrict__ ad2, const float* __restrict__ b2,
    const float* __restrict__ Wf1, const float* __restrict__ bf1,
    const float* __restrict__ Wf2, const float* __restrict__ bf2,
    uint32_t* __restrict__ maskT, float* __restrict__ node2,
    float* __restrict__ g2buf, float* __restrict__ partial4,
    float* __restrict__ out){
  __shared__ __align__(16) uint8_t smem[32768];
  cg::grid_group grid = cg::this_grid();
  int blk = blockIdx.x;
  int b = blk >> 2, q = blk & 3;
  int t = threadIdx.x;

  // ================= Phase 1 =================
  {
    uint32_t (*lm)[128][16] = (uint32_t(*)[128][16])smem;          // 16 KB
    float (*node)[8] = (float(*)[8])(smem + 16384);                // 16 KB

    {   // adj column bits: (j4 0..31)x(w 0..15)x(kh 0..1)
      int j4 = t & 31, w = (t >> 5) & 15, kh = t >> 9;
      const float* basef = adj + ((size_t)(b * N_ + (w << 5) + (kh << 4))) * N_
                               + (q * 128 + (j4 << 2));
      uint32_t m0 = 0, m1 = 0, m2 = 0, m3 = 0;
#pragma unroll
      for (int k = 0; k < 16; ++k) {
        float4 v = *(const float4*)(basef + (size_t)k * N_);
        m0 |= (v.x > 0.f ? 1u : 0u) << k;
        m1 |= (v.y > 0.f ? 1u : 0u) << k;
        m2 |= (v.z > 0.f ? 1u : 0u) << k;
        m3 |= (v.w > 0.f ? 1u : 0u) << k;
      }
      int sh = kh << 4;
      lm[kh][(j4 << 2) + 0][w] = m0 << sh;
      lm[kh][(j4 << 2) + 1][w] = m1 << sh;
      lm[kh][(j4 << 2) + 2][w] = m2 << sh;
      lm[kh][(j4 << 2) + 3][w] = m3 << sh;
    }
    if (t < N_) {   // layer-1 node transform (redundant across q; trivial)
      float xv0 = x[((size_t)(b * N_ + t)) * 3 + 0];
      float xv1 = x[((size_t)(b * N_ + t)) * 3 + 1];
      float xv2 = x[((size_t)(b * N_ + t)) * 3 + 2];
      float h[6];
#pragma unroll
      for (int c = 0; c < 6; ++c) h[c] = xv0 * W1[c] + xv1 * W1[6 + c] + xv2 * W1[12 + c];
#pragma unroll
      for (int c = 0; c < 6; ++c) node[t][c] = h[c];
      node[t][6] = h[0] * as1[0] + h[1] * as1[1] + h[2] * as1[2];
      node[t][7] = h[3] * as1[3] + h[4] * as1[4] + h[5] * as1[5];
    }
    __syncthreads();

    int w = t & 15, tg = t >> 4;   // 64 groups x 16 lanes
    float ad10 = ad1[0], ad11 = ad1[1], ad12 = ad1[2];
    float ad13 = ad1[3], ad14 = ad1[4], ad15 = ad1[5];
    float b10 = b1[0], b11 = b1[1], b12 = b1[2], b13 = b1[3], b14 = b1[4], b15 = b1[5];
    float as20 = as2[0], as21 = as2[1], as22 = as2[2];
#pragma unroll
    for (int p = 0; p < 2; ++p) {
      int jl = tg + p * 64;
      int j  = q * 128 + jl;
      uint32_t bits = lm[0][jl][w] | lm[1][jl][w];
      maskT[((size_t)(b * N_ + j)) * NW + w] = bits;
      if ((j >> 5) == w) bits |= 1u << (j & 31);

      float ed0 = node[j][0] * ad10 + node[j][1] * ad11 + node[j][2] * ad12;
      float ed1 = node[j][3] * ad13 + node[j][4] * ad14 + node[j][5] * ad15;
      float den0 = 0.f, den1 = 0.f;
      float a0 = 0.f, a1 = 0.f, a2 = 0.f, a3 = 0.f, a4 = 0.f, a5 = 0.f;
      while (bits) {
        int k = __ffs(bits) - 1;
        bits &= bits - 1;
        int i = (w << 5) + k;
        float e0 = __expf(lrelu(node[i][6] + ed0));
        float e1 = __expf(lrelu(node[i][7] + ed1));
        den0 += e0; den1 += e1;
        a0 += e0 * node[i][0]; a1 += e0 * node[i][1]; a2 += e0 * node[i][2];
        a3 += e1 * node[i][3]; a4 += e1 * node[i][4]; a5 += e1 * node[i][5];
      }
#pragma unroll
      for (int m = 1; m < 16; m <<= 1) {
        den0 += __shfl_xor(den0, m); den1 += __shfl_xor(den1, m);
        a0 += __shfl_xor(a0, m); a1 += __shfl_xor(a1, m); a2 += __shfl_xor(a2, m);
        a3 += __shfl_xor(a3, m); a4 += __shfl_xor(a4, m); a5 += __shfl_xor(a5, m);
      }
      float r0 = 1.f / den0, r1 = 1.f / den1;
      float g0 = fmaxf(a0 * r0 + b10, 0.f);
      float g1v = fmaxf(a1 * r0 + b11, 0.f);
      float g2v = fmaxf(a2 * r0 + b12, 0.f);
      float g3 = fmaxf(a3 * r1 + b13, 0.f);
      float g4 = fmaxf(a4 * r1 + b14, 0.f);
      float g5 = fmaxf(a5 * r1 + b15, 0.f);
      float h20 = g0*W2[0] + g1v*W2[3] + g2v*W2[6] + g3*W2[9]  + g4*W2[12] + g5*W2[15];
      float h21 = g0*W2[1] + g1v*W2[4] + g2v*W2[7] + g3*W2[10] + g4*W2[13] + g5*W2[16];
      float h22 = g0*W2[2] + g1v*W2[5] + g2v*W2[8] + g3*W2[11] + g4*W2[14] + g5*W2[17];
      float es2 = h20 * as20 + h21 * as21 + h22 * as22;
      if (w < 4) {
        float outv = (w == 0) ? h20 : (w == 1) ? h21 : (w == 2) ? h22 : es2;
        node2[((size_t)(b * N_ + j)) * 4 + w] = outv;
      }
    }
  }
  __threadfence();
  grid.sync();

  // ================= Phase 2: GAT-2 aggregation =================
  {
    float (*sn)[4] = (float(*)[4])smem;                 // 8 KB
    uint32_t (*smq)[16] = (uint32_t(*)[16])(smem + 8192); // 8 KB
    if (t < 512) {
      float4 v = ((const float4*)(node2 + (size_t)b * N_ * 4))[t];
      sn[t][0] = v.x; sn[t][1] = v.y; sn[t][2] = v.z; sn[t][3] = v.w;
    } else {
      ((uint4*)smq)[t - 512] = ((const uint4*)(maskT + ((size_t)b * N_ + q * 128) * NW))[t - 512];
    }
    __syncthreads();

    int w = t & 15, tg = t >> 4;
    float ad20 = ad2[0], ad21 = ad2[1], ad22 = ad2[2];
    float b20 = b2[0], b21 = b2[1], b22 = b2[2];
#pragma unroll
    for (int p = 0; p < 2; ++p) {
      int jl = tg + p * 64;
      int j  = q * 128 + jl;
      uint32_t bits = smq[jl][w];
      if ((j >> 5) == w) bits |= 1u << (j & 31);
      float ed = sn[j][0] * ad20 + sn[j][1] * ad21 + sn[j][2] * ad22;
      float den = 0.f, a0 = 0.f, a1 = 0.f, a2 = 0.f;
      while (bits) {
        int k = __ffs(bits) - 1;
        bits &= bits - 1;
        int i = (w << 5) + k;
        float e = __expf(lrelu(sn[i][3] + ed));
        den += e;
        a0 += e * sn[i][0]; a1 += e * sn[i][1]; a2 += e * sn[i][2];
      }
#pragma unroll
      for (int m = 1; m < 16; m <<= 1) {
        den += __shfl_xor(den, m);
        a0 += __shfl_xor(a0, m); a1 += __shfl_xor(a1, m); a2 += __shfl_xor(a2, m);
      }
      if (w < 3) {
        float rr = 1.f / den;
        float v = (w == 0 ? a0 : w == 1 ? a1 : a2) * rr + (w == 0 ? b20 : w == 1 ? b21 : b22);
        g2buf[((size_t)(b * N_ + j)) * 3 + w] = v;
      }
    }
  }
  __threadfence();
  grid.sync();

  // ================= Phase 3: MLP layer 1, k-quarter =================
  {
    float* feat = (float*)smem;                       // 551 floats
    float (*red)[128] = (float(*)[128])(smem + 4096); // 16 KB
    int k0 = q * KQTR;
    if (t < KQTR) {
      int k = k0 + t;
      float v;
      if (k < N_)        v = idx[(size_t)b * N_ + k];
      else if (k < 2048) v = g2buf[(size_t)b * 1536 + (k - N_)];
      else               v = y[(size_t)b * (M2 * 3) + (k - 2048)];
      feat[t] = v;
    }
    __syncthreads();

    int kq = t >> 5, ug = t & 31;         // 32 k-groups x 32 u-float4
    int kstart = kq * 18;
    int kend = min(18, KQTR - kstart);    // last group short / empty
    const float4* W4 = (const float4*)Wf1;
    float a0 = 0.f, a1 = 0.f, a2 = 0.f, a3 = 0.f;
#pragma unroll
    for (int k2 = 0; k2 < 18; ++k2) {
      if (k2 < kend) {
        float fv = feat[kstart + k2];
        float4 w = W4[(size_t)(k0 + kstart + k2) * 32 + ug];
        a0 += fv * w.x; a1 += fv * w.y; a2 += fv * w.z; a3 += fv * w.w;
      }
    }
    *(float4*)&red[kq][ug * 4] = make_float4(a0, a1, a2, a3);
    __syncthreads();
    if (t < MLPH) {
      float s = 0.f;
#pragma unroll
      for (int g = 0; g < 32; ++g) s += red[g][t];
      partial4[((size_t)b * 4 + q) * MLPH + t] = s;
    }
  }
  __threadfence();
  grid.sync();

  // ================= Phase 4: MLP layer 2, output quarter =================
  {
    float* partl = (float*)smem;                        // 512 floats
    float* hid   = (float*)(smem + 2048);               // 128 floats
    float (*red2)[128] = (float(*)[128])(smem + 4096);  // 16 KB
    if (t < 128) ((float4*)partl)[t] = ((const float4*)(partial4 + (size_t)b * 512))[t];
    __syncthreads();
    if (t < MLPH) {
      float s = bf1[t] + partl[t] + partl[128 + t] + partl[256 + t] + partl[384 + t];
      hid[t] = fmaxf(s, 0.f);
    }
    __syncthreads();

    int kh = t >> 5, ug = t & 31;        // 32 k-groups (4 k each) x 32 o-float4
    const float4* W4 = (const float4*)Wf2;
    float a0 = 0.f, a1 = 0.f, a2 = 0.f, a3 = 0.f;
#pragma unroll
    for (int k2 = 0; k2 < 4; ++k2) {
      int kk = kh * 4 + k2;
      float hv = hid[kk];
      float4 w = W4[(size_t)kk * 128 + q * 32 + ug];
      a0 += hv * w.x; a1 += hv * w.y; a2 += hv * w.z; a3 += hv * w.w;
    }
    *(float4*)&red2[kh][ug * 4] = make_float4(a0, a1, a2, a3);
    __syncthreads();
    if (t < 128) {
      float s = bf2[q * 128 + t];
#pragma unroll
      for (int g = 0; g < 32; ++g) s += red2[g][t];
      out[(size_t)b * NACT + q * 128 + t] = s;
    }
  }
}

extern "C" void kernel_launch(void* const* d_in, const int* in_sizes, int n_in,
                              void* d_out, int out_size, void* d_ws, size_t ws_size,
                              hipStream_t stream) {
  const float* idx = (const float*)d_in[0];
  const float* x   = (const float*)d_in[1];
  const float* y   = (const float*)d_in[2];
  const float* adj = (const float*)d_in[3];
  const float* W1  = (const float*)d_in[4];
  const float* as1 = (const float*)d_in[5];
  const float* ad1 = (const float*)d_in[6];
  const float* b1  = (const float*)d_in[7];
  const float* W2  = (const float*)d_in[8];
  const float* as2 = (const float*)d_in[9];
  const float* ad2 = (const float*)d_in[10];
  const float* b2  = (const float*)d_in[11];
  const float* Wf1 = (const float*)d_in[12];
  const float* bf1 = (const float*)d_in[13];
  const float* Wf2 = (const float*)d_in[14];
  const float* bf2 = (const float*)d_in[15];
  float* out = (float*)d_out;

  uint8_t* ws = (uint8_t*)d_ws;
  uint32_t* maskT  = (uint32_t*)ws;                            // 2 MB
  float* node2     = (float*)(ws + 2097152);                   // 512 KB
  float* g2buf     = (float*)(ws + 2097152 + 524288);          // 384 KB
  float* partial4  = (float*)(ws + 2097152 + 524288 + 393216); // 128 KB

  void* args[] = {
    (void*)&adj, (void*)&x, (void*)&idx, (void*)&y,
    (void*)&W1, (void*)&as1, (void*)&ad1, (void*)&b1,
    (void*)&W2, (void*)&as2, (void*)&ad2, (void*)&b2,
    (void*)&Wf1, (void*)&bf1, (void*)&Wf2, (void*)&bf2,
    (void*)&maskT, (void*)&node2, (void*)&g2buf, (void*)&partial4,
    (void*)&out
  };
  hipLaunchCooperativeKernel((const void*)kmega, dim3(256), dim3(1024), args, 0, stream);
}

// Round 10
// 123.880 us; speedup vs baseline: 2.4904x; 2.4904x over previous
//
#include <hip/hip_runtime.h>
#include <hip/hip_bf16.h>
#include <stdint.h>

#define B_    64
#define N_    512
#define M2    52      // M_PARAM + 2
#define MLPH  128
#define NACT  512
#define FC_IN 2204    // 512 + 512*3 + 52*3
#define NCH   18      // feat k-chunks of 128
#define NEG   0.2f
#define NW    16      // mask words per target (512/32)

__device__ __forceinline__ float lrelu(float v){ return v > 0.f ? v : NEG * v; }

// ---------------- Kernel 1: adj -> bitmask + GAT layer 1 + transform 2 ----------------
// Grid: (8 j-tiles, 64 b), 512 threads. Also zeroes the per-batch ticket counters.
__global__ __launch_bounds__(512) void kfuse1(const float* __restrict__ adj,
                                              const float* __restrict__ x,
                                              const float* __restrict__ W1,
                                              const float* __restrict__ as1,
                                              const float* __restrict__ ad1,
                                              const float* __restrict__ b1,
                                              const float* __restrict__ W2,
                                              const float* __restrict__ as2,
                                              uint32_t* __restrict__ maskT,
                                              float* __restrict__ node2,
                                              uint32_t* __restrict__ cnt){
  __shared__ uint32_t lm[2][64][16];   // 8 KB
  __shared__ float node[N_][8];        // 16 KB
  int b  = blockIdx.y;
  int j0 = blockIdx.x * 64;
  int t  = threadIdx.x;

  if (blockIdx.x == 0 && t == 0) cnt[b] = 0;   // ticket reset (K2 runs after K1 fully drains)

  {
    int j4 = t & 15;
    int w  = (t >> 4) & 15;
    int kh = t >> 8;
    const float* basef = adj + ((size_t)(b * N_ + (w << 5) + (kh << 4))) * N_ + (j0 + (j4 << 2));
    uint32_t m0 = 0, m1 = 0, m2 = 0, m3 = 0;
#pragma unroll
    for (int k = 0; k < 16; ++k) {
      float4 v = *(const float4*)(basef + (size_t)k * N_);
      m0 |= (v.x > 0.f ? 1u : 0u) << k;
      m1 |= (v.y > 0.f ? 1u : 0u) << k;
      m2 |= (v.z > 0.f ? 1u : 0u) << k;
      m3 |= (v.w > 0.f ? 1u : 0u) << k;
    }
    int sh = kh << 4;
    lm[kh][(j4 << 2) + 0][w] = m0 << sh;
    lm[kh][(j4 << 2) + 1][w] = m1 << sh;
    lm[kh][(j4 << 2) + 2][w] = m2 << sh;
    lm[kh][(j4 << 2) + 3][w] = m3 << sh;
  }

  {
    float xv0 = x[((size_t)(b * N_ + t)) * 3 + 0];
    float xv1 = x[((size_t)(b * N_ + t)) * 3 + 1];
    float xv2 = x[((size_t)(b * N_ + t)) * 3 + 2];
    float h[6];
#pragma unroll
    for (int c = 0; c < 6; ++c) h[c] = xv0 * W1[c] + xv1 * W1[6 + c] + xv2 * W1[12 + c];
#pragma unroll
    for (int c = 0; c < 6; ++c) node[t][c] = h[c];
    node[t][6] = h[0] * as1[0] + h[1] * as1[1] + h[2] * as1[2];
    node[t][7] = h[3] * as1[3] + h[4] * as1[4] + h[5] * as1[5];
  }
  __syncthreads();

  int w  = t & 15;
  int tg = t >> 4;
  float ad10 = ad1[0], ad11 = ad1[1], ad12 = ad1[2];
  float ad13 = ad1[3], ad14 = ad1[4], ad15 = ad1[5];
  float b10 = b1[0], b11 = b1[1], b12 = b1[2], b13 = b1[3], b14 = b1[4], b15 = b1[5];
  float as20 = as2[0], as21 = as2[1], as22 = as2[2];

#pragma unroll
  for (int p = 0; p < 2; ++p) {
    int jj = tg + p * 32;
    int j  = j0 + jj;
    uint32_t bits = lm[0][jj][w] | lm[1][jj][w];
    maskT[((size_t)(b * N_ + j)) * NW + w] = bits;
    if ((j >> 5) == w) bits |= 1u << (j & 31);

    float ed0 = node[j][0] * ad10 + node[j][1] * ad11 + node[j][2] * ad12;
    float ed1 = node[j][3] * ad13 + node[j][4] * ad14 + node[j][5] * ad15;

    float den0 = 0.f, den1 = 0.f;
    float a0 = 0.f, a1 = 0.f, a2 = 0.f, a3 = 0.f, a4 = 0.f, a5 = 0.f;
    while (bits) {
      int k = __ffs(bits) - 1;
      bits &= bits - 1;
      int i = (w << 5) + k;
      float e0 = __expf(lrelu(node[i][6] + ed0));
      float e1 = __expf(lrelu(node[i][7] + ed1));
      den0 += e0; den1 += e1;
      a0 += e0 * node[i][0]; a1 += e0 * node[i][1]; a2 += e0 * node[i][2];
      a3 += e1 * node[i][3]; a4 += e1 * node[i][4]; a5 += e1 * node[i][5];
    }
#pragma unroll
    for (int m = 1; m < 16; m <<= 1) {
      den0 += __shfl_xor(den0, m); den1 += __shfl_xor(den1, m);
      a0 += __shfl_xor(a0, m); a1 += __shfl_xor(a1, m); a2 += __shfl_xor(a2, m);
      a3 += __shfl_xor(a3, m); a4 += __shfl_xor(a4, m); a5 += __shfl_xor(a5, m);
    }
    float r0 = 1.f / den0, r1 = 1.f / den1;
    float g0 = fmaxf(a0 * r0 + b10, 0.f);
    float g1v = fmaxf(a1 * r0 + b11, 0.f);
    float g2v = fmaxf(a2 * r0 + b12, 0.f);
    float g3 = fmaxf(a3 * r1 + b13, 0.f);
    float g4 = fmaxf(a4 * r1 + b14, 0.f);
    float g5 = fmaxf(a5 * r1 + b15, 0.f);
    float h20 = g0*W2[0] + g1v*W2[3] + g2v*W2[6] + g3*W2[9]  + g4*W2[12] + g5*W2[15];
    float h21 = g0*W2[1] + g1v*W2[4] + g2v*W2[7] + g3*W2[10] + g4*W2[13] + g5*W2[16];
    float h22 = g0*W2[2] + g1v*W2[5] + g2v*W2[8] + g3*W2[11] + g4*W2[14] + g5*W2[17];
    float es2 = h20 * as20 + h21 * as21 + h22 * as22;
    if (w < 4) {
      float outv = (w == 0) ? h20 : (w == 1) ? h21 : (w == 2) ? h22 : es2;
      node2[((size_t)(b * N_ + j)) * 4 + w] = outv;
    }
  }
}

// ---------------- Kernel 2: back half, one kernel, last-block-done MLP2 ----------------
// Grid: (18 chunks, 64 b), 256 threads.
// g-chunks (4<=c<16) aggregate their own <=44 targets (parallel staging), all chunks
// compute MLP1 partials; the 18th finisher per batch runs MLP2 inline.
__global__ __launch_bounds__(256) void kback2(const float* __restrict__ idx,
                                              const float* __restrict__ y,
                                              const float* __restrict__ node2,
                                              const float* __restrict__ ad2,
                                              const float* __restrict__ b2,
                                              const uint32_t* __restrict__ maskT,
                                              const float* __restrict__ Wf1,
                                              const float* __restrict__ bf1,
                                              const float* __restrict__ Wf2,
                                              const float* __restrict__ bf2,
                                              float* __restrict__ partial,
                                              uint32_t* __restrict__ cnt,
                                              float* __restrict__ out){
  __shared__ float sn[N_][4];          // 8 KB (g-chunks)
  __shared__ uint32_t smq[44][NW];     // 2.75 KB
  __shared__ float gloc[44][3];
  __shared__ float fs[128];
  __shared__ float pr[8][128];         // 4 KB (MLP1 reduce; reused by MLP2 tail)
  __shared__ float spart[NCH * MLPH];  // 9 KB (MLP2 tail)
  __shared__ float hid[MLPH];
  __shared__ uint32_t ticket;
  int c = blockIdx.x, b = blockIdx.y, t = threadIdx.x;

  if (c >= 4 && c < 16) {
    // ---- parallel staging: 2 f4 (node2) + 1 u4 (mask rows), all issued up-front ----
    int kg0 = c * 128 - 512;
    int j0n = kg0 / 3;
    int j1n = (kg0 + 127) / 3;
    int nrow = j1n - j0n + 1;          // <= 44
    const float4* nsrc = (const float4*)(node2 + (size_t)b * N_ * 4);
    const uint4*  msrc = (const uint4*)(maskT + ((size_t)b * N_ + j0n) * NW);
    float4 n0 = nsrc[t];
    float4 n1 = nsrc[t + 256];
    uint4 mv = make_uint4(0u, 0u, 0u, 0u);
    if (t < nrow * 4) mv = msrc[t];
    sn[t][0] = n0.x; sn[t][1] = n0.y; sn[t][2] = n0.z; sn[t][3] = n0.w;
    sn[t + 256][0] = n1.x; sn[t + 256][1] = n1.y; sn[t + 256][2] = n1.z; sn[t + 256][3] = n1.w;
    if (t < nrow * 4) ((uint4*)smq)[t] = mv;
    __syncthreads();

    // ---- aggregate this chunk's targets: 16 groups x 16 lanes, 3 rounds ----
    int w = t & 15, grp = t >> 4;
    float ad20 = ad2[0], ad21 = ad2[1], ad22 = ad2[2];
    float b20 = b2[0], b21 = b2[1], b22 = b2[2];
#pragma unroll
    for (int rr = 0; rr < 3; ++rr) {
      int ji = grp + rr * 16;
      if (ji < nrow) {
        int j = j0n + ji;
        uint32_t bits = smq[ji][w];
        if ((j >> 5) == w) bits |= 1u << (j & 31);
        float ed = sn[j][0] * ad20 + sn[j][1] * ad21 + sn[j][2] * ad22;
        float den = 0.f, a0 = 0.f, a1 = 0.f, a2 = 0.f;
        while (bits) {
          int k = __ffs(bits) - 1;
          bits &= bits - 1;
          int i = (w << 5) + k;
          float e = __expf(lrelu(sn[i][3] + ed));
          den += e;
          a0 += e * sn[i][0]; a1 += e * sn[i][1]; a2 += e * sn[i][2];
        }
#pragma unroll
        for (int m = 1; m < 16; m <<= 1) {
          den += __shfl_xor(den, m);
          a0 += __shfl_xor(a0, m); a1 += __shfl_xor(a1, m); a2 += __shfl_xor(a2, m);
        }
        if (w < 3) {
          float rinv = 1.f / den;
          gloc[ji][w] = (w == 0 ? a0 : w == 1 ? a1 : a2) * rinv
                      + (w == 0 ? b20 : w == 1 ? b21 : b22);
        }
      }
    }
    __syncthreads();
    if (t < 128) {
      int kg = kg0 + t;
      int j = kg / 3, comp = kg - 3 * j;
      fs[t] = gloc[j - j0n][comp];
    }
  } else {
    if (t < 128) {
      int k = c * 128 + t;
      float v = 0.f;
      if (k < N_)                      v = idx[(size_t)b * N_ + k];
      else if (k >= 2048 && k < FC_IN) v = y[(size_t)b * (M2 * 3) + (k - 2048)];
      fs[t] = v;
    }
  }
  __syncthreads();

  // ---- MLP layer 1 partials (proven R8 path) ----
  {
    int kq = t >> 5, ug = t & 31;
    const float4* wrow = (const float4*)(Wf1 + ((size_t)(c * 128 + kq * 16)) * MLPH) + ug;
    float a0 = 0.f, a1 = 0.f, a2 = 0.f, a3 = 0.f;
    if (c < 17) {
#pragma unroll
      for (int k2 = 0; k2 < 16; ++k2) {
        float fv = fs[kq * 16 + k2];
        float4 w = wrow[k2 * 32];
        a0 += fv * w.x; a1 += fv * w.y; a2 += fv * w.z; a3 += fv * w.w;
      }
    } else {
      int kend = min(16, (FC_IN - 17 * 128) - kq * 16);   // kq=0:16, kq=1:12, else <=0
      for (int k2 = 0; k2 < kend; ++k2) {
        float fv = fs[kq * 16 + k2];
        float4 w = wrow[k2 * 32];
        a0 += fv * w.x; a1 += fv * w.y; a2 += fv * w.z; a3 += fv * w.w;
      }
    }
    *(float4*)&pr[kq][ug * 4] = make_float4(a0, a1, a2, a3);
  }
  __syncthreads();
  if (t < 128) {
    float s = 0.f;
#pragma unroll
    for (int q = 0; q < 8; ++q) s += pr[q][t];
    partial[((size_t)b * NCH + c) * MLPH + t] = s;
  }
  __syncthreads();
  __threadfence();                       // release: partial visible device-wide

  if (t == 0) ticket = atomicAdd(&cnt[b], 1u);
  __syncthreads();

  if (ticket == NCH - 1) {
    // ---- last finisher for batch b: MLP layer 2 ----
    __threadfence();                     // acquire: see all 18 partials
    const float4* psrc = (const float4*)(partial + (size_t)b * NCH * MLPH);
    float4 p0 = psrc[t];
    float4 p1 = psrc[t + 256];
    float4 p2 = (t < 64) ? psrc[t + 512] : make_float4(0.f, 0.f, 0.f, 0.f);
    ((float4*)spart)[t] = p0;
    ((float4*)spart)[t + 256] = p1;
    if (t < 64) ((float4*)spart)[t + 512] = p2;
    __syncthreads();
    if (t < MLPH) {
      float s = bf1[t];
#pragma unroll
      for (int c2 = 0; c2 < NCH; ++c2) s += spart[c2 * MLPH + t];
      hid[t] = fmaxf(s, 0.f);
    }
    __syncthreads();

    int og = t & 127, kh = t >> 7;       // 2 k-halves x 128 f4-columns
    const float4* W4 = (const float4*)Wf2;
    float a0 = 0.f, a1 = 0.f, a2 = 0.f, a3 = 0.f;
#pragma unroll 8
    for (int k2 = 0; k2 < 64; ++k2) {
      int kk = kh * 64 + k2;
      float hv = hid[kk];
      float4 w = W4[(size_t)kk * 128 + og];
      a0 += hv * w.x; a1 += hv * w.y; a2 += hv * w.z; a3 += hv * w.w;
    }
    ((float4*)pr)[kh * 128 + og] = make_float4(a0, a1, a2, a3);
    __syncthreads();
    if (t < 128) {
      float4 u = ((float4*)pr)[t];
      float4 v = ((float4*)pr)[128 + t];
      float4 bb = ((const float4*)bf2)[t];
      float4 r;
      r.x = u.x + v.x + bb.x;
      r.y = u.y + v.y + bb.y;
      r.z = u.z + v.z + bb.z;
      r.w = u.w + v.w + bb.w;
      ((float4*)(out + (size_t)b * NACT))[t] = r;
    }
  }
}

extern "C" void kernel_launch(void* const* d_in, const int* in_sizes, int n_in,
                              void* d_out, int out_size, void* d_ws, size_t ws_size,
                              hipStream_t stream) {
  const float* idx = (const float*)d_in[0];
  const float* x   = (const float*)d_in[1];
  const float* y   = (const float*)d_in[2];
  const float* adj = (const float*)d_in[3];
  const float* W1  = (const float*)d_in[4];
  const float* as1 = (const float*)d_in[5];
  const float* ad1 = (const float*)d_in[6];
  const float* b1  = (const float*)d_in[7];
  const float* W2  = (const float*)d_in[8];
  const float* as2 = (const float*)d_in[9];
  const float* ad2 = (const float*)d_in[10];
  const float* b2  = (const float*)d_in[11];
  const float* Wf1 = (const float*)d_in[12];
  const float* bf1 = (const float*)d_in[13];
  const float* Wf2 = (const float*)d_in[14];
  const float* bf2 = (const float*)d_in[15];
  float* out = (float*)d_out;

  uint8_t* ws = (uint8_t*)d_ws;
  uint32_t* maskT   = (uint32_t*)ws;                       // 2 MB
  float* node2      = (float*)(ws + 2097152);              // 512 KB
  float* partial    = (float*)(ws + 2097152 + 524288);     // 576 KB
  uint32_t* cnt     = (uint32_t*)(ws + 2097152 + 524288 + 589824);  // 256 B

  hipLaunchKernelGGL(kfuse1, dim3(8, B_), dim3(512), 0, stream,
                     adj, x, W1, as1, ad1, b1, W2, as2, maskT, node2, cnt);
  hipLaunchKernelGGL(kback2, dim3(NCH, B_), dim3(256), 0, stream,
                     idx, y, node2, ad2, b2, maskT, Wf1, bf1, Wf2, bf2,
                     partial, cnt, out);
}

// Round 11
// 30.809 us; speedup vs baseline: 10.0135x; 4.0209x over previous
//
#include <hip/hip_runtime.h>
#include <hip/hip_bf16.h>
#include <stdint.h>

#define B_    64
#define N_    512
#define M2    52      // M_PARAM + 2
#define MLPH  128
#define NACT  512
#define FC_IN 2204    // 512 + 512*3 + 52*3
#define NCH   18      // feat k-chunks of 128
#define NEG   0.2f
#define NW    16      // mask words per target (512/32)

__device__ __forceinline__ float lrelu(float v){ return v > 0.f ? v : NEG * v; }

// ---------------- Kernel 1: adj -> bitmask + GAT layer 1 + transform 2 ----------------
// Grid: (8 j-tiles, 64 b), 512 threads.
__global__ __launch_bounds__(512) void kfuse1(const float* __restrict__ adj,
                                              const float* __restrict__ x,
                                              const float* __restrict__ W1,
                                              const float* __restrict__ as1,
                                              const float* __restrict__ ad1,
                                              const float* __restrict__ b1,
                                              const float* __restrict__ W2,
                                              const float* __restrict__ as2,
                                              uint32_t* __restrict__ maskT,
                                              float* __restrict__ node2){
  __shared__ uint32_t lm[2][64][16];   // 8 KB
  __shared__ float node[N_][8];        // 16 KB
  int b  = blockIdx.y;
  int j0 = blockIdx.x * 64;
  int t  = threadIdx.x;

  {
    int j4 = t & 15;
    int w  = (t >> 4) & 15;
    int kh = t >> 8;
    const float* basef = adj + ((size_t)(b * N_ + (w << 5) + (kh << 4))) * N_ + (j0 + (j4 << 2));
    uint32_t m0 = 0, m1 = 0, m2 = 0, m3 = 0;
#pragma unroll
    for (int k = 0; k < 16; ++k) {
      float4 v = *(const float4*)(basef + (size_t)k * N_);
      m0 |= (v.x > 0.f ? 1u : 0u) << k;
      m1 |= (v.y > 0.f ? 1u : 0u) << k;
      m2 |= (v.z > 0.f ? 1u : 0u) << k;
      m3 |= (v.w > 0.f ? 1u : 0u) << k;
    }
    int sh = kh << 4;
    lm[kh][(j4 << 2) + 0][w] = m0 << sh;
    lm[kh][(j4 << 2) + 1][w] = m1 << sh;
    lm[kh][(j4 << 2) + 2][w] = m2 << sh;
    lm[kh][(j4 << 2) + 3][w] = m3 << sh;
  }

  {
    float xv0 = x[((size_t)(b * N_ + t)) * 3 + 0];
    float xv1 = x[((size_t)(b * N_ + t)) * 3 + 1];
    float xv2 = x[((size_t)(b * N_ + t)) * 3 + 2];
    float h[6];
#pragma unroll
    for (int c = 0; c < 6; ++c) h[c] = xv0 * W1[c] + xv1 * W1[6 + c] + xv2 * W1[12 + c];
#pragma unroll
    for (int c = 0; c < 6; ++c) node[t][c] = h[c];
    node[t][6] = h[0] * as1[0] + h[1] * as1[1] + h[2] * as1[2];
    node[t][7] = h[3] * as1[3] + h[4] * as1[4] + h[5] * as1[5];
  }
  __syncthreads();

  int w  = t & 15;
  int tg = t >> 4;
  float ad10 = ad1[0], ad11 = ad1[1], ad12 = ad1[2];
  float ad13 = ad1[3], ad14 = ad1[4], ad15 = ad1[5];
  float b10 = b1[0], b11 = b1[1], b12 = b1[2], b13 = b1[3], b14 = b1[4], b15 = b1[5];
  float as20 = as2[0], as21 = as2[1], as22 = as2[2];

#pragma unroll
  for (int p = 0; p < 2; ++p) {
    int jj = tg + p * 32;
    int j  = j0 + jj;
    uint32_t bits = lm[0][jj][w] | lm[1][jj][w];
    maskT[((size_t)(b * N_ + j)) * NW + w] = bits;
    if ((j >> 5) == w) bits |= 1u << (j & 31);

    float ed0 = node[j][0] * ad10 + node[j][1] * ad11 + node[j][2] * ad12;
    float ed1 = node[j][3] * ad13 + node[j][4] * ad14 + node[j][5] * ad15;

    float den0 = 0.f, den1 = 0.f;
    float a0 = 0.f, a1 = 0.f, a2 = 0.f, a3 = 0.f, a4 = 0.f, a5 = 0.f;
    while (bits) {
      int k = __ffs(bits) - 1;
      bits &= bits - 1;
      int i = (w << 5) + k;
      float e0 = __expf(lrelu(node[i][6] + ed0));
      float e1 = __expf(lrelu(node[i][7] + ed1));
      den0 += e0; den1 += e1;
      a0 += e0 * node[i][0]; a1 += e0 * node[i][1]; a2 += e0 * node[i][2];
      a3 += e1 * node[i][3]; a4 += e1 * node[i][4]; a5 += e1 * node[i][5];
    }
#pragma unroll
    for (int m = 1; m < 16; m <<= 1) {
      den0 += __shfl_xor(den0, m); den1 += __shfl_xor(den1, m);
      a0 += __shfl_xor(a0, m); a1 += __shfl_xor(a1, m); a2 += __shfl_xor(a2, m);
      a3 += __shfl_xor(a3, m); a4 += __shfl_xor(a4, m); a5 += __shfl_xor(a5, m);
    }
    float r0 = 1.f / den0, r1 = 1.f / den1;
    float g0 = fmaxf(a0 * r0 + b10, 0.f);
    float g1v = fmaxf(a1 * r0 + b11, 0.f);
    float g2v = fmaxf(a2 * r0 + b12, 0.f);
    float g3 = fmaxf(a3 * r1 + b13, 0.f);
    float g4 = fmaxf(a4 * r1 + b14, 0.f);
    float g5 = fmaxf(a5 * r1 + b15, 0.f);
    float h20 = g0*W2[0] + g1v*W2[3] + g2v*W2[6] + g3*W2[9]  + g4*W2[12] + g5*W2[15];
    float h21 = g0*W2[1] + g1v*W2[4] + g2v*W2[7] + g3*W2[10] + g4*W2[13] + g5*W2[16];
    float h22 = g0*W2[2] + g1v*W2[5] + g2v*W2[8] + g3*W2[11] + g4*W2[14] + g5*W2[17];
    float es2 = h20 * as20 + h21 * as21 + h22 * as22;
    if (w < 4) {
      float outv = (w == 0) ? h20 : (w == 1) ? h21 : (w == 2) ? h22 : es2;
      node2[((size_t)(b * N_ + j)) * 4 + w] = outv;
    }
  }
}

// ---------------- Kernel 2: in-chunk GAT-2 agg + MLP layer 1 partials ----------------
// Grid: (18 chunks, 64 b), 256 threads. No cross-block communication.
// g-chunks (4<=c<16) stage node2+mask in parallel and aggregate their own <=44 targets.
__global__ __launch_bounds__(256) void kmid(const float* __restrict__ idx,
                                            const float* __restrict__ y,
                                            const float* __restrict__ node2,
                                            const float* __restrict__ ad2,
                                            const float* __restrict__ b2,
                                            const uint32_t* __restrict__ maskT,
                                            const float* __restrict__ Wf1,
                                            float* __restrict__ partial){
  __shared__ float sn[N_][4];          // 8 KB
  __shared__ uint32_t smq[44][NW];     // 2.75 KB
  __shared__ float gloc[44][3];
  __shared__ float fs[128];
  __shared__ float pr[8][128];         // 4 KB
  int c = blockIdx.x, b = blockIdx.y, t = threadIdx.x;

  if (c >= 4 && c < 16) {
    // parallel reg-first staging: 2 f4 (node2) + up to 1 u4 (mask rows)
    int kg0 = c * 128 - 512;
    int j0n = kg0 / 3;
    int j1n = (kg0 + 127) / 3;
    int nrow = j1n - j0n + 1;          // <= 44
    const float4* nsrc = (const float4*)(node2 + (size_t)b * N_ * 4);
    const uint4*  msrc = (const uint4*)(maskT + ((size_t)b * N_ + j0n) * NW);
    float4 n0 = nsrc[t];
    float4 n1 = nsrc[t + 256];
    uint4 mv = make_uint4(0u, 0u, 0u, 0u);
    if (t < nrow * 4) mv = msrc[t];
    sn[t][0] = n0.x; sn[t][1] = n0.y; sn[t][2] = n0.z; sn[t][3] = n0.w;
    sn[t + 256][0] = n1.x; sn[t + 256][1] = n1.y; sn[t + 256][2] = n1.z; sn[t + 256][3] = n1.w;
    if (t < nrow * 4) ((uint4*)smq)[t] = mv;
    __syncthreads();

    // aggregate this chunk's targets: 16 groups x 16 lanes, 3 rounds
    int w = t & 15, grp = t >> 4;
    float ad20 = ad2[0], ad21 = ad2[1], ad22 = ad2[2];
    float b20 = b2[0], b21 = b2[1], b22 = b2[2];
#pragma unroll
    for (int rr = 0; rr < 3; ++rr) {
      int ji = grp + rr * 16;
      if (ji < nrow) {
        int j = j0n + ji;
        uint32_t bits = smq[ji][w];
        if ((j >> 5) == w) bits |= 1u << (j & 31);
        float ed = sn[j][0] * ad20 + sn[j][1] * ad21 + sn[j][2] * ad22;
        float den = 0.f, a0 = 0.f, a1 = 0.f, a2 = 0.f;
        while (bits) {
          int k = __ffs(bits) - 1;
          bits &= bits - 1;
          int i = (w << 5) + k;
          float e = __expf(lrelu(sn[i][3] + ed));
          den += e;
          a0 += e * sn[i][0]; a1 += e * sn[i][1]; a2 += e * sn[i][2];
        }
#pragma unroll
        for (int m = 1; m < 16; m <<= 1) {
          den += __shfl_xor(den, m);
          a0 += __shfl_xor(a0, m); a1 += __shfl_xor(a1, m); a2 += __shfl_xor(a2, m);
        }
        if (w < 3) {
          float rinv = 1.f / den;
          gloc[ji][w] = (w == 0 ? a0 : w == 1 ? a1 : a2) * rinv
                      + (w == 0 ? b20 : w == 1 ? b21 : b22);
        }
      }
    }
    __syncthreads();
    if (t < 128) {
      int kg = kg0 + t;
      int j = kg / 3, comp = kg - 3 * j;
      fs[t] = gloc[j - j0n][comp];
    }
  } else {
    if (t < 128) {
      int k = c * 128 + t;
      float v = 0.f;
      if (k < N_)                      v = idx[(size_t)b * N_ + k];
      else if (k >= 2048 && k < FC_IN) v = y[(size_t)b * (M2 * 3) + (k - 2048)];
      fs[t] = v;
    }
  }
  __syncthreads();

  // MLP layer 1 partials (proven R8 float4 path)
  {
    int kq = t >> 5, ug = t & 31;
    const float4* wrow = (const float4*)(Wf1 + ((size_t)(c * 128 + kq * 16)) * MLPH) + ug;
    float a0 = 0.f, a1 = 0.f, a2 = 0.f, a3 = 0.f;
    if (c < 17) {
#pragma unroll
      for (int k2 = 0; k2 < 16; ++k2) {
        float fv = fs[kq * 16 + k2];
        float4 w = wrow[k2 * 32];
        a0 += fv * w.x; a1 += fv * w.y; a2 += fv * w.z; a3 += fv * w.w;
      }
    } else {
      int kend = min(16, (FC_IN - 17 * 128) - kq * 16);   // kq=0:16, kq=1:12, else <=0
      for (int k2 = 0; k2 < kend; ++k2) {
        float fv = fs[kq * 16 + k2];
        float4 w = wrow[k2 * 32];
        a0 += fv * w.x; a1 += fv * w.y; a2 += fv * w.z; a3 += fv * w.w;
      }
    }
    *(float4*)&pr[kq][ug * 4] = make_float4(a0, a1, a2, a3);
  }
  __syncthreads();
  if (t < 128) {
    float s = 0.f;
#pragma unroll
    for (int q = 0; q < 8; ++q) s += pr[q][t];
    partial[((size_t)b * NCH + c) * MLPH + t] = s;
  }
}

// ---------------- Kernel 3: reduce + relu + MLP layer 2 (R8 verbatim) ----------------
// Grid: (4 out-quarters, 64 b), 256 threads.
__global__ __launch_bounds__(256) void kmlp2v(const float* __restrict__ partial,
                                              const float* __restrict__ bf1,
                                              const float* __restrict__ Wf2,
                                              const float* __restrict__ bf2,
                                              float* __restrict__ out){
  __shared__ float part[NCH * MLPH];   // 9 KB
  __shared__ float hid[MLPH];
  __shared__ float pr[8][128];
  int q = blockIdx.x, b = blockIdx.y, t = threadIdx.x;

  const float4* src = (const float4*)(partial + (size_t)b * NCH * MLPH);
  float4 v0 = src[t];
  float4 v1 = src[t + 256];
  float4 v2 = (t < 64) ? src[t + 512] : make_float4(0.f, 0.f, 0.f, 0.f);
  ((float4*)part)[t] = v0;
  ((float4*)part)[t + 256] = v1;
  if (t < 64) ((float4*)part)[t + 512] = v2;
  __syncthreads();
  if (t < 128) {
    float s = bf1[t];
#pragma unroll
    for (int c2 = 0; c2 < NCH; ++c2) s += part[c2 * MLPH + t];
    hid[t] = fmaxf(s, 0.f);
  }
  __syncthreads();

  int kh = t >> 5, ug = t & 31;
  const float4* wrow = (const float4*)(Wf2 + (size_t)(kh * 16) * NACT + q * 128) + ug;
  float a0 = 0.f, a1 = 0.f, a2 = 0.f, a3 = 0.f;
#pragma unroll
  for (int k2 = 0; k2 < 16; ++k2) {
    float hv = hid[kh * 16 + k2];
    float4 w = wrow[k2 * 128];
    a0 += hv * w.x; a1 += hv * w.y; a2 += hv * w.z; a3 += hv * w.w;
  }
  *(float4*)&pr[kh][ug * 4] = make_float4(a0, a1, a2, a3);
  __syncthreads();
  if (t < 128) {
    float s = bf2[q * 128 + t];
#pragma unroll
    for (int h = 0; h < 8; ++h) s += pr[h][t];
    out[(size_t)b * NACT + q * 128 + t] = s;
  }
}

extern "C" void kernel_launch(void* const* d_in, const int* in_sizes, int n_in,
                              void* d_out, int out_size, void* d_ws, size_t ws_size,
                              hipStream_t stream) {
  const float* idx = (const float*)d_in[0];
  const float* x   = (const float*)d_in[1];
  const float* y   = (const float*)d_in[2];
  const float* adj = (const float*)d_in[3];
  const float* W1  = (const float*)d_in[4];
  const float* as1 = (const float*)d_in[5];
  const float* ad1 = (const float*)d_in[6];
  const float* b1  = (const float*)d_in[7];
  const float* W2  = (const float*)d_in[8];
  const float* as2 = (const float*)d_in[9];
  const float* ad2 = (const float*)d_in[10];
  const float* b2  = (const float*)d_in[11];
  const float* Wf1 = (const float*)d_in[12];
  const float* bf1 = (const float*)d_in[13];
  const float* Wf2 = (const float*)d_in[14];
  const float* bf2 = (const float*)d_in[15];
  float* out = (float*)d_out;

  uint8_t* ws = (uint8_t*)d_ws;
  uint32_t* maskT = (uint32_t*)ws;                       // 2 MB
  float* node2    = (float*)(ws + 2097152);              // 512 KB
  float* partial  = (float*)(ws + 2097152 + 524288);     // 576 KB

  hipLaunchKernelGGL(kfuse1, dim3(8, B_),   dim3(512), 0, stream,
                     adj, x, W1, as1, ad1, b1, W2, as2, maskT, node2);
  hipLaunchKernelGGL(kmid,   dim3(NCH, B_), dim3(256), 0, stream,
                     idx, y, node2, ad2, b2, maskT, Wf1, partial);
  hipLaunchKernelGGL(kmlp2v, dim3(4, B_),   dim3(256), 0, stream,
                     partial, bf1, Wf2, bf2, out);
}